// Round 1
// baseline (6131.322 us; speedup 1.0000x reference)
//
#include <hip/hip_runtime.h>

#define B 4
#define T 8192
#define RES 256
#define SKIPC 512
#define NCLSC 256
#define NLAYERS 30
#define T0 5120
#define TBUF 3072
#define WIN 3070
#define TILE 32

// h0[b][c][t-T0] = W[c,0,0]*x[t-1] + W[c,0,1]*x[t] + b[c], t in [5122, 8191]
__global__ __launch_bounds__(256) void start_kernel(
    const float* __restrict__ x, const float* __restrict__ Wst,
    const float* __restrict__ bst, float* __restrict__ h0)
{
    int gid = blockIdx.x * 256 + threadIdx.x;
    int tt = gid % WIN;
    int rest = gid / WIN;
    int c = rest % RES;
    int b = rest / RES;
    int t = 5122 + tt;
    float v = Wst[2*c] * x[b*T + t - 1] + Wst[2*c+1] * x[b*T + t] + bst[c];
    h0[(b*RES + c)*TBUF + (t - T0)] = v;
}

// One dilated-conv + gate + residual + (skip at t=8191) layer.
// Block: 256 threads = 4 waves; wave w owns columns [8w, 8w+8); lane owns
// channels {lane, lane+64, lane+128, lane+192}. LDS reads in the GEMM loops
// are all-lanes-same-address (broadcast, conflict-free).
__global__ __launch_bounds__(256) void layer_kernel(
    const float* __restrict__ hA, float* __restrict__ hB,
    const float* __restrict__ Wd, const float* __restrict__ bd,
    const float* __restrict__ Wr, const float* __restrict__ br,
    const float* __restrict__ Ws, const float* __restrict__ bs,
    float* __restrict__ skip, int dil, int s_out)
{
    __shared__ float lds[16384];           // 64 KB: hcur[256][32] | hdil[256][32]
    float* __restrict__ hcur = lds;
    float* __restrict__ hdil = lds + 8192;

    const int tid  = threadIdx.x;
    const int tile = blockIdx.x;
    const int b    = blockIdx.y;
    const int tbase = 8160 - TILE * tile;  // absolute t of column 0 (tile 0 ends at 8191)
    const int tib   = tbase - T0;
    const float* __restrict__ hAb = hA + (size_t)b * RES * TBUF;

    // Cooperative fill, consecutive LDS addresses per lane -> conflict-free.
    // Clamped reads only happen for columns below the window (discarded later).
    #pragma unroll 4
    for (int p = 0; p < 32; ++p) {
        int flat = p * 256 + tid;
        int cin = flat >> 5, j = flat & 31;
        int t1 = tib + j;
        int t2 = t1 - dil;
        t1 = t1 < 0 ? 0 : t1;
        t2 = t2 < 0 ? 0 : t2;
        hcur[flat] = hAb[cin * TBUF + t1];
        hdil[flat] = hAb[cin * TBUF + t2];
    }
    __syncthreads();

    const int lane = tid & 63;
    const int wv   = tid >> 6;
    const int jb   = wv * 8;

    const float* __restrict__ w0p = Wd + (size_t)(lane      ) * 512;
    const float* __restrict__ w1p = Wd + (size_t)(lane +  64) * 512;
    const float* __restrict__ w2p = Wd + (size_t)(lane + 128) * 512;
    const float* __restrict__ w3p = Wd + (size_t)(lane + 192) * 512;

    float acc[4][8];
    #pragma unroll
    for (int cc = 0; cc < 4; ++cc) {
        float bv = bd[lane + 64*cc];
        #pragma unroll
        for (int j = 0; j < 8; ++j) acc[cc][j] = bv;
    }

    // Dilated conv as GEMM: d[c][col] += Wd[c][cin][0]*h(t-dil) + Wd[c][cin][1]*h(t)
    #pragma unroll 2
    for (int cin = 0; cin < 256; ++cin) {
        const float4 hc0 = *(const float4*)(hcur + cin*32 + jb);
        const float4 hc1 = *(const float4*)(hcur + cin*32 + jb + 4);
        const float4 hd0 = *(const float4*)(hdil + cin*32 + jb);
        const float4 hd1 = *(const float4*)(hdil + cin*32 + jb + 4);
        const float hc[8] = {hc0.x,hc0.y,hc0.z,hc0.w,hc1.x,hc1.y,hc1.z,hc1.w};
        const float hd[8] = {hd0.x,hd0.y,hd0.z,hd0.w,hd1.x,hd1.y,hd1.z,hd1.w};
        const float2 w[4] = {
            *(const float2*)(w0p + cin*2), *(const float2*)(w1p + cin*2),
            *(const float2*)(w2p + cin*2), *(const float2*)(w3p + cin*2)};
        #pragma unroll
        for (int cc = 0; cc < 4; ++cc)
            #pragma unroll
            for (int j = 0; j < 8; ++j)
                acc[cc][j] = fmaf(w[cc].y, hc[j], fmaf(w[cc].x, hd[j], acc[cc][j]));
    }

    // gated = tanh(d)*sigmoid(d); tanh via 1 - 2/(e^{2d}+1)
    float g[4][8];
    #pragma unroll
    for (int cc = 0; cc < 4; ++cc)
        #pragma unroll
        for (int j = 0; j < 8; ++j) {
            float d = acc[cc][j];
            float sig = 1.f / (1.f + __expf(-d));
            float th  = 1.f - 2.f / (__expf(2.f*d) + 1.f);
            g[cc][j] = th * sig;
        }

    __syncthreads();                        // conv-phase LDS reads all done
    float* __restrict__ gated = lds;        // overlay: [256][36] (pad keeps b128 16B-aligned)
    #pragma unroll
    for (int cc = 0; cc < 4; ++cc)
        #pragma unroll
        for (int j = 0; j < 8; ++j)
            gated[(lane + 64*cc)*36 + jb + j] = g[cc][j];
    __syncthreads();

    // Residual: h' = h + Wr * gated
    const float* __restrict__ r0p = Wr + (size_t)(lane      ) * 256;
    const float* __restrict__ r1p = Wr + (size_t)(lane +  64) * 256;
    const float* __restrict__ r2p = Wr + (size_t)(lane + 128) * 256;
    const float* __restrict__ r3p = Wr + (size_t)(lane + 192) * 256;
    float acc2[4][8];
    #pragma unroll
    for (int cc = 0; cc < 4; ++cc) {
        float bv = br[lane + 64*cc];
        #pragma unroll
        for (int j = 0; j < 8; ++j) acc2[cc][j] = bv;
    }
    #pragma unroll 2
    for (int cin = 0; cin < 256; ++cin) {
        const float4 g0 = *(const float4*)(gated + cin*36 + jb);
        const float4 g1 = *(const float4*)(gated + cin*36 + jb + 4);
        const float gg[8] = {g0.x,g0.y,g0.z,g0.w,g1.x,g1.y,g1.z,g1.w};
        const float w[4] = {r0p[cin], r1p[cin], r2p[cin], r3p[cin]};
        #pragma unroll
        for (int cc = 0; cc < 4; ++cc)
            #pragma unroll
            for (int j = 0; j < 8; ++j)
                acc2[cc][j] = fmaf(w[cc], gg[j], acc2[cc][j]);
    }

    float* __restrict__ hBb = hB + (size_t)b * RES * TBUF;
    #pragma unroll
    for (int cc = 0; cc < 4; ++cc) {
        const int c = lane + 64*cc;
        #pragma unroll
        for (int j = 0; j < 8; ++j) {
            int t = tbase + jb + j;
            if (t >= s_out) {
                int ti = t - T0;
                hBb[c*TBUF + ti] = hAb[c*TBUF + ti] + acc2[cc][j];
            }
        }
    }

    // Skip contribution only needed at t = 8191 (tile 0, LDS column 31).
    // One block per batch does it -> plain read-modify-write across layers is safe.
    if (tile == 0) {
        for (int o = tid; o < SKIPC; o += 256) {
            const float* __restrict__ wsr = Ws + (size_t)o * 256;
            float a = bs[o];
            #pragma unroll 4
            for (int cin = 0; cin < 256; ++cin)
                a = fmaf(wsr[cin], gated[cin*36 + 31], a);
            skip[b*SKIPC + o] += a;
        }
    }
}

// out[b] = W2 * relu(W1 * relu(skip[b]) + b1) + b2
__global__ __launch_bounds__(256) void end_kernel(
    const float* __restrict__ skip,
    const float* __restrict__ W1, const float* __restrict__ b1,
    const float* __restrict__ W2, const float* __restrict__ b2,
    float* __restrict__ out)
{
    __shared__ float s[SKIPC];
    __shared__ float e1[SKIPC];
    const int tid = threadIdx.x;
    const int b = blockIdx.x;
    for (int o = tid; o < SKIPC; o += 256) s[o] = fmaxf(skip[b*SKIPC + o], 0.f);
    __syncthreads();
    for (int o = tid; o < SKIPC; o += 256) {
        const float* w = W1 + (size_t)o * SKIPC;
        float a = b1[o];
        #pragma unroll 4
        for (int c = 0; c < SKIPC; ++c) a = fmaf(w[c], s[c], a);
        e1[o] = fmaxf(a, 0.f);
    }
    __syncthreads();
    {
        const float* w = W2 + (size_t)tid * SKIPC;
        float a = b2[tid];
        #pragma unroll 4
        for (int o = 0; o < SKIPC; ++o) a = fmaf(w[o], e1[o], a);
        out[b*NCLSC + tid] = a;
    }
}

extern "C" void kernel_launch(void* const* d_in, const int* in_sizes, int n_in,
                              void* d_out, int out_size, void* d_ws, size_t ws_size,
                              hipStream_t stream)
{
    const float* x    = (const float*)d_in[0];
    const float* Wst  = (const float*)d_in[1];
    const float* bst  = (const float*)d_in[2];
    const float* Wd   = (const float*)d_in[3];
    const float* bd   = (const float*)d_in[4];
    const float* Wr   = (const float*)d_in[5];
    const float* br   = (const float*)d_in[6];
    const float* Ws   = (const float*)d_in[7];
    const float* bs   = (const float*)d_in[8];
    const float* W1   = (const float*)d_in[9];
    const float* b1   = (const float*)d_in[10];
    const float* W2   = (const float*)d_in[11];
    const float* b2   = (const float*)d_in[12];
    float* out = (float*)d_out;

    float* buf0 = (float*)d_ws;                       // [4][256][3072]
    float* buf1 = buf0 + (size_t)B*RES*TBUF;          // [4][256][3072]
    float* skip = buf1 + (size_t)B*RES*TBUF;          // [4][512]

    hipMemsetAsync(skip, 0, B*SKIPC*sizeof(float), stream);
    start_kernel<<<dim3((B*RES*WIN)/256), 256, 0, stream>>>(x, Wst, bst, buf0);

    int rem[NLAYERS+1];
    rem[NLAYERS] = 0;
    for (int i = NLAYERS-1; i >= 0; --i) rem[i] = rem[i+1] + (1 << (i % 10));

    for (int i = 0; i < NLAYERS; ++i) {
        int dil = 1 << (i % 10);
        int s_out = 8191 - rem[i+1];     // first t whose output this layer must produce
        int L = 8192 - s_out;
        int ntiles = (L + TILE - 1) / TILE;
        const float* hA = (i & 1) ? buf1 : buf0;
        float*       hB = (i & 1) ? buf0 : buf1;
        layer_kernel<<<dim3(ntiles, B), 256, 0, stream>>>(
            hA, hB,
            Wd + (size_t)i*RES*RES*2, bd + (size_t)i*RES,
            Wr + (size_t)i*RES*RES,   br + (size_t)i*RES,
            Ws + (size_t)i*SKIPC*RES, bs + (size_t)i*SKIPC,
            skip, dil, s_out);
    }
    end_kernel<<<dim3(B), 256, 0, stream>>>(skip, W1, b1, W2, b2, out);
}

// Round 2
// 1138.547 us; speedup vs baseline: 5.3852x; 5.3852x over previous
//
#include <hip/hip_runtime.h>

#define BATCH 4
#define T 8192
#define RES 256
#define SKIPC 512
#define NCLSC 256
#define NLAYERS 30
#define T0 5120
#define TBUF 3072
#define NT 32

typedef __attribute__((ext_vector_type(8))) short short8x;   // 8 bf16 (4 VGPRs)
typedef __attribute__((ext_vector_type(4))) float floatx4;   // MFMA C/D
typedef unsigned short ushort_t;
typedef unsigned long long ull;

__device__ __forceinline__ ushort_t f2bf(float f) {          // RNE float->bf16
    unsigned u = __float_as_uint(f);
    u += 0x7fffu + ((u >> 16) & 1u);
    return (ushort_t)(u >> 16);
}
__device__ __forceinline__ float bf2f(ushort_t h) {
    return __uint_as_float(((unsigned)h) << 16);
}

// Reorder/cast weights once per call.
// WdP[l][cout][kk*256+cin] (bf16), WrP[l][cout][cin] (bf16),
// WsT[l][cin][o] (bf16), W1T[c][o] (f32), W2T[o][cls] (f32)
__global__ __launch_bounds__(256) void prep_kernel(
    const float* __restrict__ Wd, const float* __restrict__ Wr,
    const float* __restrict__ Ws, const float* __restrict__ W1,
    const float* __restrict__ W2,
    ushort_t* __restrict__ WdP, ushort_t* __restrict__ WrP,
    ushort_t* __restrict__ WsT, float* __restrict__ W1T, float* __restrict__ W2T)
{
    long id = (long)blockIdx.x * 256 + threadIdx.x;
    const long R0 = 30L * 131072, R1 = 30L * 65536, R2 = 30L * 131072;
    const long R3 = 262144, R4 = 131072;
    if (id < R0) {
        int k = id & 511; long lc = id >> 9;        // lc = l*256+cout
        int kk = k >> 8, cin = k & 255;
        WdP[id] = f2bf(Wd[lc * 512 + cin * 2 + kk]);
        return;
    }
    id -= R0;
    if (id < R1) { WrP[id] = f2bf(Wr[id]); return; }
    id -= R1;
    if (id < R2) {
        int o = id & 511; long rest = id >> 9; int cin = (int)(rest & 255); long l = rest >> 8;
        WsT[id] = f2bf(Ws[(l * 512 + o) * 256 + cin]);
        return;
    }
    id -= R2;
    if (id < R3) { int o = id & 511; int c = (int)(id >> 9); W1T[id] = W1[o * 512 + c]; return; }
    id -= R3;
    if (id < R4) { int cls = id & 255; int o = (int)(id >> 8); W2T[id] = W2[cls * 512 + o]; }
}

// h0[b][t][c] for t in [5120, 8191], fp32 + bf16 copies.
__global__ __launch_bounds__(256) void start_kernel(
    const float* __restrict__ x, const float* __restrict__ Wst,
    const float* __restrict__ bst, float* __restrict__ hf, ushort_t* __restrict__ hb)
{
    int id = blockIdx.x * 256 + threadIdx.x;      // [b][ti][c]
    int c = id & 255;
    int ti = (id >> 8) % TBUF;
    int b  = (id >> 8) / TBUF;
    int t = T0 + ti;
    float v = Wst[2 * c] * x[b * T + t - 1] + Wst[2 * c + 1] * x[b * T + t] + bst[c];
    hf[id] = v;
    hb[id] = f2bf(v);
}

// One WaveNet layer on MFMA. Block: 512 thr = 8 waves, tile 256(M) x 32(N).
// Wave wv owns rows [32wv,32wv+32), cols all 32 (2x2 of 16x16x32 mfma).
// No barrier in K-loops; gated transposes through LDS for the residual GEMM.
__global__ __launch_bounds__(512) void layer_kernel(
    float* __restrict__ hf,                 // fp32 residual stream, in-place
    const ushort_t* __restrict__ hbA,       // bf16 in  [b][t][c]
    ushort_t* __restrict__ hbB,             // bf16 out [b][t][c]
    const ushort_t* __restrict__ WdP,       // [256][512] this layer
    const float* __restrict__ bd,
    const ushort_t* __restrict__ WrP,       // [256][256] this layer
    const float* __restrict__ br,
    float* __restrict__ gstoreL,            // [4][256] gated @ t=8191, fp32
    int dil, int s_out)
{
    __shared__ ushort_t gl[NT][264];        // gated [n][cin], stride 264: 16B rows, ~4-way max

    const int tid = threadIdx.x;
    const int wv = tid >> 6, lane = tid & 63;
    const int quad = lane >> 4, l16 = lane & 15;
    const int tile = blockIdx.x, b = blockIdx.y;
    const int tb = 8192 - NT * (tile + 1);
    const int mb = wv * 32;

    float* __restrict__ hfb = hf + (size_t)b * TBUF * RES;
    const ushort_t* __restrict__ hA = hbA + (size_t)b * TBUF * RES;
    ushort_t* __restrict__ hB = hbB + (size_t)b * TBUF * RES;

    // per-lane column indices (nt=0,1), taps clamped into buffer
    const int t0 = tb + l16, t1 = t0 + 16;
    int i0a = t0 - dil - T0; i0a = i0a < 0 ? 0 : i0a;
    int i0b = t0 - T0;       i0b = i0b < 0 ? 0 : i0b;
    int i1a = t1 - dil - T0; i1a = i1a < 0 ? 0 : i1a;
    int i1b = t1 - T0;       i1b = i1b < 0 ? 0 : i1b;
    const ushort_t* pB0a = hA + (size_t)i0a * RES + quad * 8;
    const ushort_t* pB0b = hA + (size_t)i0b * RES + quad * 8;
    const ushort_t* pB1a = hA + (size_t)i1a * RES + quad * 8;
    const ushort_t* pB1b = hA + (size_t)i1b * RES + quad * 8;

    const ushort_t* pA0 = WdP + (size_t)(mb + l16) * 512 + quad * 8;
    const ushort_t* pA1 = pA0 + 16 * 512;

    floatx4 acc00, acc01, acc10, acc11;
    {
        float4 b0 = *(const float4*)(bd + mb + quad * 4);
        float4 b1 = *(const float4*)(bd + mb + 16 + quad * 4);
        acc00 = acc01 = (floatx4){b0.x, b0.y, b0.z, b0.w};
        acc10 = acc11 = (floatx4){b1.x, b1.y, b1.z, b1.w};
    }

    // Conv GEMM: K=512 (k<256: tap t-dil, k>=256: tap t)
    #pragma unroll
    for (int s = 0; s < 16; ++s) {
        const int co = (s & 7) * 32;
        short8x a0 = *(const short8x*)(pA0 + s * 32);
        short8x a1 = *(const short8x*)(pA1 + s * 32);
        short8x bb0 = (s < 8) ? *(const short8x*)(pB0a + co) : *(const short8x*)(pB0b + co);
        short8x bb1 = (s < 8) ? *(const short8x*)(pB1a + co) : *(const short8x*)(pB1b + co);
        acc00 = __builtin_amdgcn_mfma_f32_16x16x32_bf16(a0, bb0, acc00, 0, 0, 0);
        acc10 = __builtin_amdgcn_mfma_f32_16x16x32_bf16(a1, bb0, acc10, 0, 0, 0);
        acc01 = __builtin_amdgcn_mfma_f32_16x16x32_bf16(a0, bb1, acc01, 0, 0, 0);
        acc11 = __builtin_amdgcn_mfma_f32_16x16x32_bf16(a1, bb1, acc11, 0, 0, 0);
    }

    // gate -> LDS (bf16, B-operand layout for residual GEMM); capture t=8191 col fp32
    #pragma unroll
    for (int mt = 0; mt < 2; ++mt) {
        #pragma unroll
        for (int nt = 0; nt < 2; ++nt) {
            floatx4 a = mt == 0 ? (nt == 0 ? acc00 : acc01) : (nt == 0 ? acc10 : acc11);
            float gf[4];
            ull pk = 0;
            #pragma unroll
            for (int r = 0; r < 4; ++r) {
                float d = a[r];
                float sig = 1.f / (1.f + __expf(-d));
                float th = 1.f - 2.f / (__expf(2.f * d) + 1.f);
                gf[r] = th * sig;
                pk |= ((ull)f2bf(gf[r])) << (16 * r);
            }
            const int n = nt * 16 + l16;
            const int m = mb + mt * 16 + quad * 4;
            *(ull*)&gl[n][m] = pk;
            if (tile == 0 && n == 31) {            // t == 8191
                float4 g4 = {gf[0], gf[1], gf[2], gf[3]};
                *(float4*)&gstoreL[b * RES + m] = g4;
            }
        }
    }
    __syncthreads();

    // Residual GEMM: h' = h + Wr @ gated, K=256
    const ushort_t* pR0 = WrP + (size_t)(mb + l16) * 256 + quad * 8;
    const ushort_t* pR1 = pR0 + 16 * 256;
    const ushort_t* pG0 = &gl[l16][quad * 8];
    const ushort_t* pG1 = &gl[16 + l16][quad * 8];

    floatx4 r00, r01, r10, r11;
    {
        float4 b0 = *(const float4*)(br + mb + quad * 4);
        float4 b1 = *(const float4*)(br + mb + 16 + quad * 4);
        r00 = r01 = (floatx4){b0.x, b0.y, b0.z, b0.w};
        r10 = r11 = (floatx4){b1.x, b1.y, b1.z, b1.w};
    }
    #pragma unroll
    for (int s = 0; s < 8; ++s) {
        short8x a0 = *(const short8x*)(pR0 + s * 32);
        short8x a1 = *(const short8x*)(pR1 + s * 32);
        short8x g0 = *(const short8x*)(pG0 + s * 32);
        short8x g1 = *(const short8x*)(pG1 + s * 32);
        r00 = __builtin_amdgcn_mfma_f32_16x16x32_bf16(a0, g0, r00, 0, 0, 0);
        r10 = __builtin_amdgcn_mfma_f32_16x16x32_bf16(a1, g0, r10, 0, 0, 0);
        r01 = __builtin_amdgcn_mfma_f32_16x16x32_bf16(a0, g1, r01, 0, 0, 0);
        r11 = __builtin_amdgcn_mfma_f32_16x16x32_bf16(a1, g1, r11, 0, 0, 0);
    }

    // Epilogue: in-place fp32 residual add + bf16 copy; only valid columns
    #pragma unroll
    for (int nt = 0; nt < 2; ++nt) {
        const int t = tb + nt * 16 + l16;
        if (t < s_out) continue;
        const size_t base = (size_t)(t - T0) * RES;
        #pragma unroll
        for (int mt = 0; mt < 2; ++mt) {
            const int m = mb + mt * 16 + quad * 4;
            floatx4 ad = mt == 0 ? (nt == 0 ? r00 : r01) : (nt == 0 ? r10 : r11);
            float4 ho = *(const float4*)(hfb + base + m);
            float4 hn = {ho.x + ad[0], ho.y + ad[1], ho.z + ad[2], ho.w + ad[3]};
            *(float4*)(hfb + base + m) = hn;
            ull pk = (ull)f2bf(hn.x) | ((ull)f2bf(hn.y) << 16)
                   | ((ull)f2bf(hn.z) << 32) | ((ull)f2bf(hn.w) << 48);
            *(ull*)(hB + base + m) = pk;
        }
    }
}

// All 30 skip matvecs in parallel: block (l,b), thread o: skip[b][o] += bs + Ws[l]@g[l,b]
__global__ __launch_bounds__(512) void skip_kernel(
    const ushort_t* __restrict__ WsT, const float* __restrict__ bs,
    const float* __restrict__ gstore, float* __restrict__ skip)
{
    const int l = blockIdx.x, b = blockIdx.y, o = threadIdx.x;
    const ushort_t* w = WsT + (size_t)l * 131072;        // [cin][512]
    const float* g = gstore + (size_t)(l * BATCH + b) * RES;
    float a = bs[l * SKIPC + o];
    #pragma unroll 4
    for (int cin = 0; cin < RES; ++cin)
        a = fmaf(bf2f(w[cin * SKIPC + o]), g[cin], a);
    atomicAdd(&skip[b * SKIPC + o], a);
}

// out[b] = W2 @ relu(W1 @ relu(skip) + b1) + b2  (transposed weights, coalesced)
__global__ __launch_bounds__(512) void end_kernel(
    const float* __restrict__ skip, const float* __restrict__ W1T,
    const float* __restrict__ b1, const float* __restrict__ W2T,
    const float* __restrict__ b2, float* __restrict__ out)
{
    __shared__ float s[SKIPC];
    __shared__ float e1[SKIPC];
    const int b = blockIdx.x, tid = threadIdx.x;
    s[tid] = fmaxf(skip[b * SKIPC + tid], 0.f);
    __syncthreads();
    float a = b1[tid];
    #pragma unroll 4
    for (int c = 0; c < SKIPC; ++c) a = fmaf(W1T[c * SKIPC + tid], s[c], a);
    e1[tid] = fmaxf(a, 0.f);
    __syncthreads();
    if (tid < NCLSC) {
        float a2 = b2[tid];
        #pragma unroll 4
        for (int o = 0; o < SKIPC; ++o) a2 = fmaf(W2T[o * NCLSC + tid], e1[o], a2);
        out[b * NCLSC + tid] = a2;
    }
}

extern "C" void kernel_launch(void* const* d_in, const int* in_sizes, int n_in,
                              void* d_out, int out_size, void* d_ws, size_t ws_size,
                              hipStream_t stream)
{
    const float* x   = (const float*)d_in[0];
    const float* Wst = (const float*)d_in[1];
    const float* bst = (const float*)d_in[2];
    const float* Wd  = (const float*)d_in[3];
    const float* bd  = (const float*)d_in[4];
    const float* Wr  = (const float*)d_in[5];
    const float* br  = (const float*)d_in[6];
    const float* Ws  = (const float*)d_in[7];
    const float* bs  = (const float*)d_in[8];
    const float* W1  = (const float*)d_in[9];
    const float* b1  = (const float*)d_in[10];
    const float* W2  = (const float*)d_in[11];
    const float* b2  = (const float*)d_in[12];
    float* out = (float*)d_out;

    char* w = (char*)d_ws;
    float* hf     = (float*)w;     w += (size_t)BATCH * TBUF * RES * 4;   // 12.6 MB
    ushort_t* hb0 = (ushort_t*)w;  w += (size_t)BATCH * TBUF * RES * 2;   // 6.3 MB
    ushort_t* hb1 = (ushort_t*)w;  w += (size_t)BATCH * TBUF * RES * 2;   // 6.3 MB
    ushort_t* WdP = (ushort_t*)w;  w += (size_t)NLAYERS * RES * 512 * 2;  // 7.9 MB
    ushort_t* WrP = (ushort_t*)w;  w += (size_t)NLAYERS * RES * RES * 2;  // 3.9 MB
    ushort_t* WsT = (ushort_t*)w;  w += (size_t)NLAYERS * RES * SKIPC * 2;// 7.9 MB
    float* W1T    = (float*)w;     w += (size_t)SKIPC * SKIPC * 4;        // 1.0 MB
    float* W2T    = (float*)w;     w += (size_t)SKIPC * NCLSC * 4;        // 0.5 MB
    float* gstore = (float*)w;     w += (size_t)NLAYERS * BATCH * RES * 4;// 123 KB
    float* skip   = (float*)w;     w += (size_t)BATCH * SKIPC * 4;        // 8 KB

    prep_kernel<<<39936, 256, 0, stream>>>(Wd, Wr, Ws, W1, W2, WdP, WrP, WsT, W1T, W2T);
    start_kernel<<<(BATCH * TBUF * RES) / 256, 256, 0, stream>>>(x, Wst, bst, hf, hb0);
    hipMemsetAsync(skip, 0, BATCH * SKIPC * 4, stream);

    int rem[NLAYERS + 1];
    rem[NLAYERS] = 0;
    for (int i = NLAYERS - 1; i >= 0; --i) rem[i] = rem[i + 1] + (1 << (i % 10));

    for (int i = 0; i < NLAYERS; ++i) {
        int dil = 1 << (i % 10);
        int s_out = 8191 - rem[i + 1];
        int L = 8192 - s_out;
        int ntiles = (L + NT - 1) / NT;
        const ushort_t* hin = (i & 1) ? hb1 : hb0;
        ushort_t* hout = (i & 1) ? hb0 : hb1;
        layer_kernel<<<dim3(ntiles, BATCH), 512, 0, stream>>>(
            hf, hin, hout,
            WdP + (size_t)i * RES * 512, bd + (size_t)i * RES,
            WrP + (size_t)i * RES * RES, br + (size_t)i * RES,
            gstore + (size_t)i * BATCH * RES, dil, s_out);
    }
    skip_kernel<<<dim3(NLAYERS, BATCH), 512, 0, stream>>>(WsT, bs, gstore, skip);
    end_kernel<<<BATCH, 512, 0, stream>>>(skip, W1T, b1, W2T, b2, out);
}

// Round 3
// 624.544 us; speedup vs baseline: 9.8173x; 1.8230x over previous
//
#include <hip/hip_runtime.h>

#define BATCH 4
#define T 8192
#define RES 256
#define SKIPC 512
#define NCLSC 256
#define NLAYERS 30
#define T0 5120
#define TBUF 3072
#define NT 32
#define STR 264               // LDS row stride in shorts (528 B): 2-way banks, 16B-aligned
#define TAPSZ (NT * STR)      // 8448 shorts per tap buffer

typedef __attribute__((ext_vector_type(8))) short short8x;   // 8 bf16
typedef __attribute__((ext_vector_type(4))) float floatx4;   // MFMA C/D
typedef unsigned short ushort_t;
typedef unsigned long long ull;

__device__ __forceinline__ ushort_t f2bf(float f) {
    unsigned u = __float_as_uint(f);
    u += 0x7fffu + ((u >> 16) & 1u);
    return (ushort_t)(u >> 16);
}
__device__ __forceinline__ float bf2f(ushort_t h) {
    return __uint_as_float(((unsigned)h) << 16);
}

// Weight prep: Aswz/Rswz are stored in exact MFMA A-fragment load order so the
// kernel's A-loads are base + lane*16B (fully coalesced).
// Aswz[l][wv(8)][s(16)][f(2)][lane(64)][j(8)]; row=wv*32+f*16+(lane&15), k=s*32+(lane>>4)*8+j
// Rswz[l][wv(8)][s(8)][f(2)][lane(64)][j(8)];  same, k<256
// WsT[l][cin][o]
__global__ __launch_bounds__(256) void prep_kernel(
    const float* __restrict__ Wd, const float* __restrict__ Wr,
    const float* __restrict__ Ws,
    ushort_t* __restrict__ Aswz, ushort_t* __restrict__ Rswz,
    ushort_t* __restrict__ WsT)
{
    long id = (long)blockIdx.x * 256 + threadIdx.x;
    const long R0 = 30L * 131072, R1 = 30L * 65536, R2 = 30L * 131072;
    if (id < R0) {
        long l = id >> 17; int r = (int)(id & 131071);
        int j = r & 7, lane = (r >> 3) & 63, f = (r >> 9) & 1, s = (r >> 10) & 15, wv = r >> 14;
        int row = wv * 32 + f * 16 + (lane & 15);
        int k = s * 32 + (lane >> 4) * 8 + j;
        int cin = k & 255, kk = k >> 8;
        Aswz[id] = f2bf(Wd[((l * 256 + row) * 256 + cin) * 2 + kk]);
        return;
    }
    id -= R0;
    if (id < R1) {
        long l = id >> 16; int r = (int)(id & 65535);
        int j = r & 7, lane = (r >> 3) & 63, f = (r >> 9) & 1, s = (r >> 10) & 7, wv = r >> 13;
        int row = wv * 32 + f * 16 + (lane & 15);
        int k = s * 32 + (lane >> 4) * 8 + j;
        Rswz[id] = f2bf(Wr[(l * 256 + row) * 256 + k]);
        return;
    }
    id -= R1;
    if (id < R2) {
        int o = (int)(id & 511); long rest = id >> 9; int cin = (int)(rest & 255); long l = rest >> 8;
        WsT[id] = f2bf(Ws[(l * 512 + o) * 256 + cin]);
    }
}

// h0[b][t][c] for t in [5120, 8191], fp32 + bf16 copies.
__global__ __launch_bounds__(256) void start_kernel(
    const float* __restrict__ x, const float* __restrict__ Wst,
    const float* __restrict__ bst, float* __restrict__ hf, ushort_t* __restrict__ hb)
{
    int id = blockIdx.x * 256 + threadIdx.x;
    int c = id & 255;
    int ti = (id >> 8) % TBUF;
    int b  = (id >> 8) / TBUF;
    int t = T0 + ti;
    float v = Wst[2 * c] * x[b * T + t - 1] + Wst[2 * c + 1] * x[b * T + t] + bst[c];
    hf[id] = v;
    hb[id] = f2bf(v);
}

// One WaveNet layer. 512 thr = 8 waves, tile 256(M) x 32(N).
// B-taps staged to LDS via coalesced fill; A-weights pre-swizzled (coalesced loads).
__global__ __launch_bounds__(512) void layer_kernel(
    float* __restrict__ hf,
    const ushort_t* __restrict__ hbA,
    ushort_t* __restrict__ hbB,
    const ushort_t* __restrict__ Aswz,
    const float* __restrict__ bd,
    const ushort_t* __restrict__ Rswz,
    const float* __restrict__ br,
    float* __restrict__ gstoreL,
    int dil, int s_out)
{
    __shared__ __align__(16) ushort_t st[2 * TAPSZ];   // 33.8 KB; gated overlays tap0 later

    const int tid = threadIdx.x;
    const int wv = tid >> 6, lane = tid & 63;
    const int quad = lane >> 4, l16 = lane & 15;
    const int tile = blockIdx.x, b = blockIdx.y;
    const int tb = 8192 - NT * (tile + 1);
    const int mb = wv * 32;

    float* __restrict__ hfb = hf + (size_t)b * TBUF * RES;
    const ushort_t* __restrict__ hA = hbA + (size_t)b * TBUF * RES;
    ushort_t* __restrict__ hB = hbB + (size_t)b * TBUF * RES;

    // Stage tap0 (t-dil) and tap1 (t): 32 rows x 512 B each, coalesced 16 B chunks.
    #pragma unroll
    for (int tp = 0; tp < 2; ++tp) {
        const int dsub = tp ? 0 : dil;
        #pragma unroll
        for (int p = 0; p < 2; ++p) {
            int c = p * 512 + tid;
            int row = c >> 5, off = (c & 31) * 8;
            int tt = tb + row - dsub - T0;
            tt = tt < 0 ? 0 : tt;            // junk cols are discarded in epilogue
            *(float4*)&st[tp * TAPSZ + row * STR + off] =
                *(const float4*)(hA + (size_t)tt * RES + off);
        }
    }
    __syncthreads();

    floatx4 acc00, acc01, acc10, acc11;
    {
        float4 c0 = *(const float4*)(bd + mb + quad * 4);
        float4 c1 = *(const float4*)(bd + mb + 16 + quad * 4);
        acc00 = acc01 = (floatx4){c0.x, c0.y, c0.z, c0.w};
        acc10 = acc11 = (floatx4){c1.x, c1.y, c1.z, c1.w};
    }

    const ushort_t* aw = Aswz + (size_t)wv * 16384 + lane * 8;
    const int u0 = l16 * STR + quad * 8;
    const int u1 = u0 + 16 * STR;

    // Conv GEMM: K=512 (s<8: tap0 = t-dil, s>=8: tap1 = t)
    #pragma unroll
    for (int s = 0; s < 16; ++s) {
        const int tbs = (s < 8 ? 0 : TAPSZ) + (s & 7) * 32;
        short8x a0 = *(const short8x*)(aw + s * 1024);
        short8x a1 = *(const short8x*)(aw + s * 1024 + 512);
        short8x g0 = *(const short8x*)&st[tbs + u0];
        short8x g1 = *(const short8x*)&st[tbs + u1];
        acc00 = __builtin_amdgcn_mfma_f32_16x16x32_bf16(a0, g0, acc00, 0, 0, 0);
        acc10 = __builtin_amdgcn_mfma_f32_16x16x32_bf16(a1, g0, acc10, 0, 0, 0);
        acc01 = __builtin_amdgcn_mfma_f32_16x16x32_bf16(a0, g1, acc01, 0, 0, 0);
        acc11 = __builtin_amdgcn_mfma_f32_16x16x32_bf16(a1, g1, acc11, 0, 0, 0);
    }
    __syncthreads();   // all conv LDS reads done before gated overlays tap0

    // gate -> LDS gl[n][cin] (overlay on tap0 region); capture t=8191 col fp32
    #pragma unroll
    for (int mt = 0; mt < 2; ++mt) {
        #pragma unroll
        for (int nt = 0; nt < 2; ++nt) {
            floatx4 a = mt == 0 ? (nt == 0 ? acc00 : acc01) : (nt == 0 ? acc10 : acc11);
            float gf[4];
            ull pk = 0;
            #pragma unroll
            for (int r = 0; r < 4; ++r) {
                float d = a[r];
                float sig = 1.f / (1.f + __expf(-d));
                float th = 1.f - 2.f / (__expf(2.f * d) + 1.f);
                gf[r] = th * sig;
                pk |= ((ull)f2bf(gf[r])) << (16 * r);
            }
            const int n = nt * 16 + l16;
            const int m = mb + mt * 16 + quad * 4;
            *(ull*)&st[n * STR + m] = pk;
            if (tile == 0 && n == 31) {
                float4 g4 = {gf[0], gf[1], gf[2], gf[3]};
                *(float4*)&gstoreL[b * RES + m] = g4;
            }
        }
    }
    __syncthreads();

    // Residual GEMM: h' = h + Wr @ gated, K=256
    const ushort_t* rw = Rswz + (size_t)wv * 8192 + lane * 8;
    floatx4 r00, r01, r10, r11;
    {
        float4 c0 = *(const float4*)(br + mb + quad * 4);
        float4 c1 = *(const float4*)(br + mb + 16 + quad * 4);
        r00 = r01 = (floatx4){c0.x, c0.y, c0.z, c0.w};
        r10 = r11 = (floatx4){c1.x, c1.y, c1.z, c1.w};
    }
    #pragma unroll
    for (int s = 0; s < 8; ++s) {
        short8x a0 = *(const short8x*)(rw + s * 1024);
        short8x a1 = *(const short8x*)(rw + s * 1024 + 512);
        short8x g0 = *(const short8x*)&st[s * 32 + u0];
        short8x g1 = *(const short8x*)&st[s * 32 + u1];
        r00 = __builtin_amdgcn_mfma_f32_16x16x32_bf16(a0, g0, r00, 0, 0, 0);
        r10 = __builtin_amdgcn_mfma_f32_16x16x32_bf16(a1, g0, r10, 0, 0, 0);
        r01 = __builtin_amdgcn_mfma_f32_16x16x32_bf16(a0, g1, r01, 0, 0, 0);
        r11 = __builtin_amdgcn_mfma_f32_16x16x32_bf16(a1, g1, r11, 0, 0, 0);
    }

    // Epilogue: in-place fp32 residual add + bf16 copy; only valid columns
    #pragma unroll
    for (int nt = 0; nt < 2; ++nt) {
        const int t = tb + nt * 16 + l16;
        if (t < s_out) continue;
        const size_t base = (size_t)(t - T0) * RES;
        #pragma unroll
        for (int mt = 0; mt < 2; ++mt) {
            const int m = mb + mt * 16 + quad * 4;
            floatx4 ad = mt == 0 ? (nt == 0 ? r00 : r01) : (nt == 0 ? r10 : r11);
            float4 ho = *(const float4*)(hfb + base + m);
            float4 hn = {ho.x + ad[0], ho.y + ad[1], ho.z + ad[2], ho.w + ad[3]};
            *(float4*)(hfb + base + m) = hn;
            ull pk = (ull)f2bf(hn.x) | ((ull)f2bf(hn.y) << 16)
                   | ((ull)f2bf(hn.z) << 32) | ((ull)f2bf(hn.w) << 48);
            *(ull*)(hB + base + m) = pk;
        }
    }
}

// All 30 skip matvecs in parallel: block (l,b), thread o
__global__ __launch_bounds__(512) void skip_kernel(
    const ushort_t* __restrict__ WsT, const float* __restrict__ bs,
    const float* __restrict__ gstore, float* __restrict__ skip)
{
    const int l = blockIdx.x, b = blockIdx.y, o = threadIdx.x;
    const ushort_t* w = WsT + (size_t)l * 131072;
    const float* g = gstore + (size_t)(l * BATCH + b) * RES;
    float a = bs[l * SKIPC + o];
    #pragma unroll 4
    for (int cin = 0; cin < RES; ++cin)
        a = fmaf(bf2f(w[cin * SKIPC + o]), g[cin], a);
    atomicAdd(&skip[b * SKIPC + o], a);
}

// e1[b][o] = relu(W1 @ relu(skip[b]) + b1); grid (B, 16), block computes 32 outputs
__global__ __launch_bounds__(256) void end1_kernel(
    const float* __restrict__ skip, const float* __restrict__ W1,
    const float* __restrict__ b1, float* __restrict__ e1ws)
{
    __shared__ float s[SKIPC];
    __shared__ float part[256];
    const int b = blockIdx.x, og = blockIdx.y, tid = threadIdx.x;
    s[tid]       = fmaxf(skip[b * SKIPC + tid], 0.f);
    s[tid + 256] = fmaxf(skip[b * SKIPC + tid + 256], 0.f);
    __syncthreads();
    const int o_l = tid >> 3, kp = tid & 7;
    const int o = og * 32 + o_l;
    const float* w = W1 + (size_t)o * SKIPC + kp * 64;
    const float* sp = s + kp * 64;
    float a = 0.f;
    #pragma unroll 8
    for (int j = 0; j < 64; ++j) a = fmaf(w[j], sp[j], a);
    part[tid] = a;
    __syncthreads();
    if (tid < 32) {
        float r = b1[og * 32 + tid];
        #pragma unroll
        for (int k = 0; k < 8; ++k) r += part[tid * 8 + k];
        e1ws[b * SKIPC + og * 32 + tid] = fmaxf(r, 0.f);
    }
}

// out[b][cls] = W2 @ e1 + b2; grid (B, 8), block computes 32 outputs
__global__ __launch_bounds__(256) void end2_kernel(
    const float* __restrict__ e1ws, const float* __restrict__ W2,
    const float* __restrict__ b2, float* __restrict__ out)
{
    __shared__ float e[SKIPC];
    __shared__ float part[256];
    const int b = blockIdx.x, og = blockIdx.y, tid = threadIdx.x;
    e[tid]       = e1ws[b * SKIPC + tid];
    e[tid + 256] = e1ws[b * SKIPC + tid + 256];
    __syncthreads();
    const int o_l = tid >> 3, kp = tid & 7;
    const int cls = og * 32 + o_l;
    const float* w = W2 + (size_t)cls * SKIPC + kp * 64;
    const float* ep = e + kp * 64;
    float a = 0.f;
    #pragma unroll 8
    for (int j = 0; j < 64; ++j) a = fmaf(w[j], ep[j], a);
    part[tid] = a;
    __syncthreads();
    if (tid < 32) {
        float r = b2[og * 32 + tid];
        #pragma unroll
        for (int k = 0; k < 8; ++k) r += part[tid * 8 + k];
        out[b * NCLSC + og * 32 + tid] = r;
    }
}

extern "C" void kernel_launch(void* const* d_in, const int* in_sizes, int n_in,
                              void* d_out, int out_size, void* d_ws, size_t ws_size,
                              hipStream_t stream)
{
    const float* x   = (const float*)d_in[0];
    const float* Wst = (const float*)d_in[1];
    const float* bst = (const float*)d_in[2];
    const float* Wd  = (const float*)d_in[3];
    const float* bd  = (const float*)d_in[4];
    const float* Wr  = (const float*)d_in[5];
    const float* br  = (const float*)d_in[6];
    const float* Ws  = (const float*)d_in[7];
    const float* bs  = (const float*)d_in[8];
    const float* W1  = (const float*)d_in[9];
    const float* b1  = (const float*)d_in[10];
    const float* W2  = (const float*)d_in[11];
    const float* b2  = (const float*)d_in[12];
    float* out = (float*)d_out;

    char* w = (char*)d_ws;
    float* hf     = (float*)w;     w += (size_t)BATCH * TBUF * RES * 4;
    ushort_t* hb0 = (ushort_t*)w;  w += (size_t)BATCH * TBUF * RES * 2;
    ushort_t* hb1 = (ushort_t*)w;  w += (size_t)BATCH * TBUF * RES * 2;
    ushort_t* Asw = (ushort_t*)w;  w += (size_t)NLAYERS * RES * 512 * 2;
    ushort_t* Rsw = (ushort_t*)w;  w += (size_t)NLAYERS * RES * RES * 2;
    ushort_t* WsT = (ushort_t*)w;  w += (size_t)NLAYERS * RES * SKIPC * 2;
    float* gstore = (float*)w;     w += (size_t)NLAYERS * BATCH * RES * 4;
    float* skip   = (float*)w;     w += (size_t)BATCH * SKIPC * 4;
    float* e1ws   = (float*)w;     w += (size_t)BATCH * SKIPC * 4;

    prep_kernel<<<38400, 256, 0, stream>>>(Wd, Wr, Ws, Asw, Rsw, WsT);
    start_kernel<<<(BATCH * TBUF * RES) / 256, 256, 0, stream>>>(x, Wst, bst, hf, hb0);
    hipMemsetAsync(skip, 0, BATCH * SKIPC * 4, stream);

    int rem[NLAYERS + 1];
    rem[NLAYERS] = 0;
    for (int i = NLAYERS - 1; i >= 0; --i) rem[i] = rem[i + 1] + (1 << (i % 10));

    for (int i = 0; i < NLAYERS; ++i) {
        int dil = 1 << (i % 10);
        int s_out = 8191 - rem[i + 1];
        int L = 8192 - s_out;
        int ntiles = (L + NT - 1) / NT;
        const ushort_t* hin = (i & 1) ? hb1 : hb0;
        ushort_t* hout = (i & 1) ? hb0 : hb1;
        layer_kernel<<<dim3(ntiles, BATCH), 512, 0, stream>>>(
            hf, hin, hout,
            Asw + (size_t)i * RES * 512, bd + (size_t)i * RES,
            Rsw + (size_t)i * RES * RES, br + (size_t)i * RES,
            gstore + (size_t)i * BATCH * RES, dil, s_out);
    }
    skip_kernel<<<dim3(NLAYERS, BATCH), 512, 0, stream>>>(WsT, bs, gstore, skip);
    end1_kernel<<<dim3(BATCH, 16), 256, 0, stream>>>(skip, W1, b1, e1ws);
    end2_kernel<<<dim3(BATCH, 8), 256, 0, stream>>>(e1ws, W2, b2, out);
}